// Round 1
// baseline (863.090 us; speedup 1.0000x reference)
//
#include <hip/hip_runtime.h>
#include <stdint.h>

#define THR 10.0f

// ---- problem sizes ----
static constexpr int T_STEPS = 20;
static constexpr int BATCH   = 8;
// layer1: 4 x 256 x 256 ; layer2: 36 x 42 x 42 ; layer3: 1 x 21 x 21

// ---- workspace layout (bytes) ----
static constexpr size_t OFF_M1 = 0;                 // 8*4*256*256*4   = 8,388,608
static constexpr size_t OFF_M2 = 8388608;           // 8*36*42*42*4    = 2,032,128
static constexpr size_t OFF_M3 = 10420736;          // 8*1*21*21*4     = 14,112
static constexpr size_t ZERO_F4 = 652178;           // (m1+m2+m3)=10,434,848 B /16
static constexpr size_t OFF_S1 = 10435072;          // u8, 2,097,152
static constexpr size_t OFF_P1 = 12532224;          // f32, 225,792
static constexpr size_t OFF_P2 = 12758016;          // u8, 127,008

__global__ __launch_bounds__(256) void zero_kernel(float4* __restrict__ p, int n4) {
    int i = blockIdx.x * 256 + threadIdx.x;
    if (i < (int)n4) p[i] = float4{0.f, 0.f, 0.f, 0.f};
}

// ============ K1: conv1(5x5, 1->4, SAME) + LIF + WTA(block2) -> s1(u8), m1 update
// grid (8,8,8)=(tileX,tileY,b), block 256 (16x16), thread = 2x2 WTA block, all 4 ch
__global__ __launch_bounds__(256) void k1_conv_lif(
    const float* __restrict__ x,      // (B,256,256) for this t
    const float* __restrict__ w1,     // (4,1,5,5)
    float* __restrict__ m1,           // (B,4,256,256)
    uint8_t* __restrict__ s1)         // (B,4,256,256)
{
    __shared__ float xs[36 * 36];
    const int tid = threadIdx.x;
    const int tx = tid & 15, ty = tid >> 4;
    const int ox = blockIdx.x * 32, oy = blockIdx.y * 32;
    const int b = blockIdx.z;
    const float* xb = x + (size_t)b * 65536;

    for (int idx = tid; idx < 1296; idx += 256) {
        int r = idx / 36, c = idx % 36;
        int gy = oy + r - 2, gx = ox + c - 2;
        float v = 0.f;
        if (gy >= 0 && gy < 256 && gx >= 0 && gx < 256) v = xb[gy * 256 + gx];
        xs[idx] = v;
    }
    __syncthreads();

    const int lx = tx * 2, ly = ty * 2;
    float p[6][6];
#pragma unroll
    for (int i = 0; i < 6; i++)
#pragma unroll
        for (int j = 0; j < 6; j++)
            p[i][j] = xs[(ly + i) * 36 + lx + j];

    float acc[4][2][2];
#pragma unroll
    for (int c = 0; c < 4; c++)
#pragma unroll
        for (int dy = 0; dy < 2; dy++)
#pragma unroll
            for (int dx = 0; dx < 2; dx++) acc[c][dy][dx] = 0.f;

#pragma unroll
    for (int c = 0; c < 4; c++)
#pragma unroll
        for (int ky = 0; ky < 5; ky++)
#pragma unroll
            for (int kx = 0; kx < 5; kx++) {
                float w = w1[c * 25 + ky * 5 + kx];
#pragma unroll
                for (int dy = 0; dy < 2; dy++)
#pragma unroll
                    for (int dx = 0; dx < 2; dx++)
                        acc[c][dy][dx] = fmaf(p[dy + ky][dx + kx], w, acc[c][dy][dx]);
            }

    // membrane integrate
    float mem[4][2][2];
#pragma unroll
    for (int c = 0; c < 4; c++) {
        size_t base = ((size_t)(b * 4 + c)) * 65536 + (size_t)(oy + ly) * 256 + (ox + lx);
#pragma unroll
        for (int dy = 0; dy < 2; dy++) {
            float2 mo = *reinterpret_cast<const float2*>(m1 + base + (size_t)dy * 256);
            mem[c][dy][0] = mo.x + acc[c][dy][0];
            mem[c][dy][1] = mo.y + acc[c][dy][1];
        }
    }

    // channel argmax per pixel (first max, strict >)
    int wc[2][2];
#pragma unroll
    for (int dy = 0; dy < 2; dy++)
#pragma unroll
        for (int dx = 0; dx < 2; dx++) {
            int w = 0; float mx = mem[0][dy][dx];
#pragma unroll
            for (int c = 1; c < 4; c++) {
                float v = mem[c][dy][dx];
                if (v > mx) { mx = v; w = c; }
            }
            wc[dy][dx] = w;
        }

    // per-channel 2x2 block max
    float bm[4];
#pragma unroll
    for (int c = 0; c < 4; c++)
        bm[c] = fmaxf(fmaxf(mem[c][0][0], mem[c][0][1]), fmaxf(mem[c][1][0], mem[c][1][1]));

    // spike + reset + leak, store
#pragma unroll
    for (int c = 0; c < 4; c++) {
        size_t base = ((size_t)(b * 4 + c)) * 65536 + (size_t)(oy + ly) * 256 + (ox + lx);
#pragma unroll
        for (int dy = 0; dy < 2; dy++) {
            float2 mn; uchar2 sp;
            {
                float m = mem[c][dy][0];
                bool s = (m >= THR) && (wc[dy][0] == c) && (m >= bm[c]);
                sp.x = s ? 1 : 0;
                float v = s ? 0.f : m;
                mn.x = fmaxf(v - 9.0f, 0.f);
            }
            {
                float m = mem[c][dy][1];
                bool s = (m >= THR) && (wc[dy][1] == c) && (m >= bm[c]);
                sp.y = s ? 1 : 0;
                float v = s ? 0.f : m;
                mn.y = fmaxf(v - 9.0f, 0.f);
            }
            *reinterpret_cast<float2*>(m1 + base + (size_t)dy * 256) = mn;
            *reinterpret_cast<uchar2*>(s1 + base + (size_t)dy * 256) = sp;
        }
    }
}

// ============ KP: maxpool 7x7 stride 6 : s1 (B,4,256,256) -> p1 (B,4,42,42) f32
__global__ __launch_bounds__(256) void kpool1(const uint8_t* __restrict__ s1,
                                              float* __restrict__ p1)
{
    int id = blockIdx.x * 256 + threadIdx.x;
    if (id >= 8 * 4 * 42 * 42) return;
    int j = id % 42, i = (id / 42) % 42, bc = id / 1764;
    const uint8_t* base = s1 + (size_t)bc * 65536 + (size_t)(i * 6) * 256 + (j * 6);
    int m = 0;
#pragma unroll
    for (int dy = 0; dy < 7; dy++)
#pragma unroll
        for (int dx = 0; dx < 7; dx++) {
            int v = base[dy * 256 + dx];
            m = v > m ? v : m;
        }
    p1[id] = (float)m;
}

// ============ K2: conv2(5x5, 4->36, SAME) + LIF + WTA(block2) + pool2(2x2==WTA block)
// grid (6,6,8) tiles of 8x8 px; block 256 = 4 waves; lane = pixel, wave-uniform channel
__global__ __launch_bounds__(256) void k2_conv_lif(
    const float* __restrict__ p1,     // (B,4,42,42)
    const float* __restrict__ w2,     // (36,4,5,5)
    float* __restrict__ m2,           // (B,36,42,42)
    uint8_t* __restrict__ p2)         // (B,36,21,21)
{
    __shared__ float ps[4 * 12 * 12];      // input patch
    __shared__ float mem_s[36 * 64];       // membranes, [c][lane]
    __shared__ float bm_s[36 * 16];        // block max   [c][blk]
    __shared__ int   wc_s[64];             // winner channel per pixel

    const int tid = threadIdx.x;
    const int ox = blockIdx.x * 8, oy = blockIdx.y * 8;
    const int b = blockIdx.z;

    for (int idx = tid; idx < 576; idx += 256) {
        int ic = idx / 144, r = (idx / 12) % 12, cc = idx % 12;
        int gy = oy + r - 2, gx = ox + cc - 2;
        float v = 0.f;
        if (gy >= 0 && gy < 42 && gx >= 0 && gx < 42)
            v = p1[((size_t)(b * 4 + ic) * 42 + gy) * 42 + gx];
        ps[idx] = v;
    }
    __syncthreads();

    const int wave = tid >> 6, lane = tid & 63;
    const int pr = lane >> 3, pc = lane & 7;
    const int gy = oy + pr, gx = ox + pc;
    const bool valid = (gy < 42) && (gx < 42);

    float pv[4][5][5];
#pragma unroll
    for (int ic = 0; ic < 4; ic++)
#pragma unroll
        for (int i = 0; i < 5; i++)
#pragma unroll
            for (int j = 0; j < 5; j++)
                pv[ic][i][j] = ps[ic * 144 + (pr + i) * 12 + (pc + j)];

    for (int cc = 0; cc < 9; cc++) {
        int c = cc * 4 + wave;                       // wave-uniform
        const float* wr = w2 + (size_t)__builtin_amdgcn_readfirstlane(c) * 100;
        float acc = 0.f;
#pragma unroll
        for (int ic = 0; ic < 4; ic++)
#pragma unroll
            for (int i = 0; i < 5; i++)
#pragma unroll
                for (int j = 0; j < 5; j++)
                    acc = fmaf(pv[ic][i][j], wr[ic * 25 + i * 5 + j], acc);
        float mem = -1e30f;
        if (valid) mem = m2[((size_t)(b * 36 + c) * 42 + gy) * 42 + gx] + acc;
        mem_s[c * 64 + lane] = mem;
    }
    __syncthreads();

    if (tid < 64) {
        float mx = mem_s[tid]; int w = 0;
        for (int c = 1; c < 36; c++) {
            float v = mem_s[c * 64 + tid];
            if (v > mx) { mx = v; w = c; }
        }
        wc_s[tid] = w;
    }
    for (int idx = tid; idx < 576; idx += 256) {
        int c = idx >> 4, blk = idx & 15;
        int l0 = (blk >> 2) * 16 + (blk & 3) * 2;
        float a = mem_s[c * 64 + l0],     bb = mem_s[c * 64 + l0 + 1];
        float d = mem_s[c * 64 + l0 + 8], e  = mem_s[c * 64 + l0 + 9];
        bm_s[idx] = fmaxf(fmaxf(a, bb), fmaxf(d, e));
    }
    __syncthreads();

    for (int idx = tid; idx < 576; idx += 256) {
        int c = idx >> 4, blk = idx & 15;
        int br = blk >> 2, bc2 = blk & 3;
        int l0 = br * 16 + bc2 * 2;
        float bm = bm_s[idx];
        uint8_t any = 0;
#pragma unroll
        for (int k = 0; k < 4; k++) {
            int dy = k >> 1, dx = k & 1;
            int l = l0 + dy * 8 + dx;
            int py = oy + 2 * br + dy, px = ox + 2 * bc2 + dx;
            if (py < 42 && px < 42) {
                float m = mem_s[c * 64 + l];
                bool s = (m >= THR) && (wc_s[l] == c) && (m >= bm);
                any |= (uint8_t)s;
                float v = s ? 0.f : m;
                m2[((size_t)(b * 36 + c) * 42 + py) * 42 + px] = fmaxf(v - 1.0f, 0.f);
            }
        }
        int gby = (oy >> 1) + br, gbx = (ox >> 1) + bc2;
        if (gby < 21 && gbx < 21)
            p2[((size_t)(b * 36 + c) * 21 + gby) * 21 + gbx] = any;
    }
}

// ============ K3: conv3(7x7, 36->1, SAME) + LIF (no WTA, leak 0) -> out, m3
// one wave per output pixel; grid 882 x 256
__global__ __launch_bounds__(256) void k3_conv_lif(
    const uint8_t* __restrict__ p2,   // (B,36,21,21)
    const float* __restrict__ w3,     // (1,36,7,7)
    float* __restrict__ m3,           // (B,441)
    float* __restrict__ out)          // (B,441) for this t
{
    int wid = blockIdx.x * 4 + (threadIdx.x >> 6);
    int lane = threadIdx.x & 63;
    if (wid >= 3528) return;
    int b = wid / 441, rem = wid % 441, r = rem / 21, col = rem % 21;
    const uint8_t* pb = p2 + (size_t)b * 36 * 441;
    float acc = 0.f;
    for (int idx = lane; idx < 1764; idx += 64) {
        int c = idx / 49, kk = idx % 49;
        int y = r + kk / 7 - 3, x2 = col + (kk % 7) - 3;
        float v = 0.f;
        if (y >= 0 && y < 21 && x2 >= 0 && x2 < 21)
            v = (float)pb[c * 441 + y * 21 + x2];
        acc = fmaf(v, w3[idx], acc);
    }
#pragma unroll
    for (int off = 32; off; off >>= 1) acc += __shfl_xor(acc, off, 64);
    if (lane == 0) {
        float mem = m3[(size_t)b * 441 + rem] + acc;
        bool s = mem >= THR;
        out[wid] = s ? 1.f : 0.f;
        float v = s ? 0.f : mem;
        m3[(size_t)b * 441 + rem] = fmaxf(v - 0.0f, 0.f);
    }
}

extern "C" void kernel_launch(void* const* d_in, const int* in_sizes, int n_in,
                              void* d_out, int out_size, void* d_ws, size_t ws_size,
                              hipStream_t stream) {
    const float* x  = (const float*)d_in[0];   // (20,8,1,256,256)
    const float* w1 = (const float*)d_in[1];   // (4,1,5,5)
    const float* w2 = (const float*)d_in[2];   // (36,4,5,5)
    const float* w3 = (const float*)d_in[3];   // (1,36,7,7)
    float* out = (float*)d_out;                // (20,8,1,21,21)
    char* ws = (char*)d_ws;

    float*   m1 = (float*)(ws + OFF_M1);
    float*   m2 = (float*)(ws + OFF_M2);
    float*   m3 = (float*)(ws + OFF_M3);
    uint8_t* s1 = (uint8_t*)(ws + OFF_S1);
    float*   p1 = (float*)(ws + OFF_P1);
    uint8_t* p2 = (uint8_t*)(ws + OFF_P2);

    zero_kernel<<<2548, 256, 0, stream>>>((float4*)ws, (int)ZERO_F4);

    for (int t = 0; t < T_STEPS; t++) {
        k1_conv_lif<<<dim3(8, 8, 8), 256, 0, stream>>>(x + (size_t)t * BATCH * 65536, w1, m1, s1);
        kpool1<<<221, 256, 0, stream>>>(s1, p1);
        k2_conv_lif<<<dim3(6, 6, 8), 256, 0, stream>>>(p1, w2, m2, p2);
        k3_conv_lif<<<882, 256, 0, stream>>>(p2, w3, m3, out + (size_t)t * 3528);
    }
}